// Round 2
// baseline (606.789 us; speedup 1.0000x reference)
//
#include <hip/hip_runtime.h>
#include <hip/hip_bf16.h>

// Problem constants (fixed by the reference).
#define B_  2
#define N_  2048
#define D_  512
#define H_  8
#define HD_ 64

typedef float  f4 __attribute__((ext_vector_type(4)));
typedef int    i4 __attribute__((ext_vector_type(4)));

// ---------------------------------------------------------------------------
// Projection GEMM: out[r, c] = sum_k in[r, k] * W[c, k] + bias[c]
// in: [4096, 512] row-major, W: [512, 512] row-major (row = output feature)
// MODE 0: out is plain [4096, 512]
// MODE 1: out is [B, H, N, HD]  (QKV layout for attention)
// Tile 128x128, BK=32, 256 threads, 8x8 micro-tile.
// ---------------------------------------------------------------------------
template <int MODE>
__device__ __forceinline__ void proj_body(
    const float* __restrict__ A, const float* __restrict__ W,
    const float* __restrict__ bias, float* __restrict__ out,
    int c0, int r0)
{
    __shared__ float As[32][132];   // [k][m]
    __shared__ float Bs[32][132];   // [k][n]

    const int tid = threadIdx.x;
    const int tx = tid & 15, ty = tid >> 4;

    float acc[8][8] = {};

    for (int kt = 0; kt < 512; kt += 32) {
        __syncthreads();
        // Stage A (rows) and W (output features) tiles, transposed to [k][m].
        #pragma unroll
        for (int l = 0; l < 4; ++l) {
            const int m  = (tid >> 3) + l * 32;     // 0..127
            const int k4 = (tid & 7) * 4;           // 0..28
            f4 ta = *(const f4*)&A[(size_t)(r0 + m) * 512 + kt + k4];
            As[k4 + 0][m] = ta[0]; As[k4 + 1][m] = ta[1];
            As[k4 + 2][m] = ta[2]; As[k4 + 3][m] = ta[3];
            f4 tw = *(const f4*)&W[(size_t)(c0 + m) * 512 + kt + k4];
            Bs[k4 + 0][m] = tw[0]; Bs[k4 + 1][m] = tw[1];
            Bs[k4 + 2][m] = tw[2]; Bs[k4 + 3][m] = tw[3];
        }
        __syncthreads();

        #pragma unroll 8
        for (int kk = 0; kk < 32; ++kk) {
            f4 a0 = *(const f4*)&As[kk][ty * 8];
            f4 a1 = *(const f4*)&As[kk][ty * 8 + 4];
            f4 b0 = *(const f4*)&Bs[kk][tx * 8];
            f4 b1 = *(const f4*)&Bs[kk][tx * 8 + 4];
            #pragma unroll
            for (int i = 0; i < 8; ++i) {
                const float av = (i < 4) ? a0[i] : a1[i - 4];
                #pragma unroll
                for (int j = 0; j < 8; ++j) {
                    const float bv = (j < 4) ? b0[j] : b1[j - 4];
                    acc[i][j] += av * bv;
                }
            }
        }
    }

    // Epilogue: add bias, store.
    #pragma unroll
    for (int i = 0; i < 8; ++i) {
        const int r = r0 + ty * 8 + i;
        const int bb = r >> 11;        // / N_
        const int n  = r & (N_ - 1);
        #pragma unroll
        for (int jj = 0; jj < 8; jj += 4) {
            const int c = c0 + tx * 8 + jj;
            f4 bv = *(const f4*)&bias[c];
            f4 o;
            o[0] = acc[i][jj + 0] + bv[0];
            o[1] = acc[i][jj + 1] + bv[1];
            o[2] = acc[i][jj + 2] + bv[2];
            o[3] = acc[i][jj + 3] + bv[3];
            if (MODE == 0) {
                *(f4*)&out[(size_t)r * 512 + c] = o;
            } else {
                const int h = c >> 6, hd = c & 63;
                *(f4*)&out[(((size_t)(bb * H_ + h)) * N_ + n) * HD_ + hd] = o;
            }
        }
    }
}

// Fused Q/K/V projections: blockIdx.z selects which projection.
__global__ __launch_bounds__(256) void qkv_kernel(
    const float* __restrict__ x,
    const float* __restrict__ Wq, const float* __restrict__ bq,
    const float* __restrict__ Wk, const float* __restrict__ bk,
    const float* __restrict__ Wv, const float* __restrict__ bv,
    float* __restrict__ Qb, float* __restrict__ Kb, float* __restrict__ Vb)
{
    const int c0 = blockIdx.x * 128;
    const int r0 = blockIdx.y * 128;
    const int z  = blockIdx.z;
    const float* W = (z == 0) ? Wq : (z == 1) ? Wk : Wv;
    const float* bb = (z == 0) ? bq : (z == 1) ? bk : bv;
    float* dst     = (z == 0) ? Qb : (z == 1) ? Kb : Vb;
    proj_body<1>(x, W, bb, dst, c0, r0);
}

__global__ __launch_bounds__(256) void proj_kernel(
    const float* __restrict__ A, const float* __restrict__ W,
    const float* __restrict__ bias, float* __restrict__ out)
{
    proj_body<0>(A, W, bias, out, blockIdx.x * 128, blockIdx.y * 128);
}

// ---------------------------------------------------------------------------
// Masked flash attention.  Q/K/V in [B, H, N, HD].  One block per
// (q-tile of 64, b*H+h).  256 threads, 4x4 micro-tile, online softmax.
// ctx written as [B, N, D].
// ---------------------------------------------------------------------------
__global__ __launch_bounds__(256) void attn_kernel(
    const float* __restrict__ Q, const float* __restrict__ K,
    const float* __restrict__ V, const int* __restrict__ adj,
    float* __restrict__ ctx)
{
    __shared__ float Qs[HD_][68];    // [d][q]
    __shared__ float KPs[64][68];    // K chunk [d][k]; reused as P [k][q]
    __shared__ float Vs[64][68];     // V chunk [k][dv]

    const int tid = threadIdx.x;
    const int tx = tid & 15, ty = tid >> 4;
    const int tx4 = tx * 4, ty4 = ty * 4;
    const int bh = blockIdx.y;              // b*H + h
    const int b  = bh >> 3;
    const int hh = bh & 7;
    const int q0 = blockIdx.x * 64;

    const float* Qbh = Q + (size_t)bh * N_ * HD_;
    const float* Kbh = K + (size_t)bh * N_ * HD_;
    const float* Vbh = V + (size_t)bh * N_ * HD_;
    const int*   adjb = adj + (size_t)b * N_ * N_;

    // Stage Q tile transposed: Qs[d][q].
    #pragma unroll
    for (int l = 0; l < 4; ++l) {
        const int q  = (tid >> 4) + l * 16;
        const int d4 = (tid & 15) * 4;
        f4 t = *(const f4*)&Qbh[(size_t)(q0 + q) * HD_ + d4];
        Qs[d4 + 0][q] = t[0]; Qs[d4 + 1][q] = t[1];
        Qs[d4 + 2][q] = t[2]; Qs[d4 + 3][q] = t[3];
    }

    float acc[4][4] = {};
    float m_r[4], l_r[4];
    const float NEG_INF = -__builtin_inff();
    #pragma unroll
    for (int i = 0; i < 4; ++i) { m_r[i] = NEG_INF; l_r[i] = 0.0f; }

    const float scale = 0.125f;   // HD^-0.5

    for (int kc = 0; kc < N_; kc += 64) {
        __syncthreads();   // previous PV done with KPs/Vs (and Qs staged, iter 0)
        // Stage K chunk transposed [d][k] and V chunk direct [k][dv].
        #pragma unroll
        for (int l = 0; l < 4; ++l) {
            const int kk = (tid >> 4) + l * 16;
            const int d4 = (tid & 15) * 4;
            f4 t = *(const f4*)&Kbh[(size_t)(kc + kk) * HD_ + d4];
            KPs[d4 + 0][kk] = t[0]; KPs[d4 + 1][kk] = t[1];
            KPs[d4 + 2][kk] = t[2]; KPs[d4 + 3][kk] = t[3];
            *(f4*)&Vs[kk][d4] = *(const f4*)&Vbh[(size_t)(kc + kk) * HD_ + d4];
        }
        __syncthreads();

        // S = Q·K^T (4x4 per thread).
        float s[4][4] = {};
        #pragma unroll 16
        for (int d = 0; d < HD_; ++d) {
            f4 a  = *(const f4*)&Qs[d][ty4];
            f4 bv = *(const f4*)&KPs[d][tx4];
            #pragma unroll
            for (int i = 0; i < 4; ++i)
                #pragma unroll
                for (int j = 0; j < 4; ++j)
                    s[i][j] += a[i] * bv[j];
        }

        // Mask + online softmax (row spread across the 16-lane tx group).
        float preg[4][4];
        #pragma unroll
        for (int i = 0; i < 4; ++i) {
            const int q = q0 + ty4 + i;
            i4 am = *(const i4*)&adjb[(size_t)q * N_ + kc + tx4];
            float sm[4];
            #pragma unroll
            for (int j = 0; j < 4; ++j)
                sm[j] = (am[j] != 0) ? s[i][j] * scale : NEG_INF;
            float mx = fmaxf(fmaxf(sm[0], sm[1]), fmaxf(sm[2], sm[3]));
            #pragma unroll
            for (int off = 1; off < 16; off <<= 1)
                mx = fmaxf(mx, __shfl_xor(mx, off));
            const float mnew = fmaxf(m_r[i], mx);
            float factor;
            if (mnew == NEG_INF) {        // entire row masked so far
                factor = 1.0f;
                preg[i][0] = preg[i][1] = preg[i][2] = preg[i][3] = 0.0f;
            } else {
                factor = __expf(m_r[i] - mnew);   // m_r = -inf -> 0
                #pragma unroll
                for (int j = 0; j < 4; ++j)
                    preg[i][j] = __expf(sm[j] - mnew);  // sm = -inf -> 0
            }
            m_r[i] = mnew;
            float rs = preg[i][0] + preg[i][1] + preg[i][2] + preg[i][3];
            #pragma unroll
            for (int off = 1; off < 16; off <<= 1)
                rs += __shfl_xor(rs, off);
            l_r[i] = l_r[i] * factor + rs;
            #pragma unroll
            for (int j = 0; j < 4; ++j) acc[i][j] *= factor;
        }

        __syncthreads();   // everyone done reading K from KPs
        // Write P into KPs as [k][q].
        #pragma unroll
        for (int i = 0; i < 4; ++i)
            #pragma unroll
            for (int j = 0; j < 4; ++j)
                KPs[tx4 + j][ty4 + i] = preg[i][j];
        __syncthreads();

        // ctx += P · V  (P: [k][q] in KPs, V: [k][dv] in Vs)
        #pragma unroll 16
        for (int kk = 0; kk < 64; ++kk) {
            f4 pp = *(const f4*)&KPs[kk][ty4];
            f4 vv = *(const f4*)&Vs[kk][tx4];
            #pragma unroll
            for (int i = 0; i < 4; ++i)
                #pragma unroll
                for (int j = 0; j < 4; ++j)
                    acc[i][j] += pp[i] * vv[j];
        }
    }

    // Epilogue: normalize by l, store ctx [B, N, D].
    #pragma unroll
    for (int i = 0; i < 4; ++i) {
        const int q = q0 + ty4 + i;
        const float inv = (l_r[i] > 0.0f) ? 1.0f / l_r[i] : 0.0f;
        f4 o;
        o[0] = acc[i][0] * inv; o[1] = acc[i][1] * inv;
        o[2] = acc[i][2] * inv; o[3] = acc[i][3] * inv;
        *(f4*)&ctx[((size_t)(b * N_ + q)) * D_ + hh * HD_ + tx4] = o;
    }
}

// ---------------------------------------------------------------------------
// Residual + LayerNorm: out = LN(x + y1) * gamma + beta.
// One wave (64 threads) per row; 8 floats per lane; two-pass in registers.
// ---------------------------------------------------------------------------
__global__ __launch_bounds__(64) void ln_kernel(
    const float* __restrict__ x, const float* __restrict__ y1,
    const float* __restrict__ gamma, const float* __restrict__ beta,
    float* __restrict__ out)
{
    const int row = blockIdx.x;
    const int tid = threadIdx.x;
    const size_t base = (size_t)row * 512 + tid * 8;

    f4 v0 = *(const f4*)&x[base]     + *(const f4*)&y1[base];
    f4 v1 = *(const f4*)&x[base + 4] + *(const f4*)&y1[base + 4];

    float s = v0[0] + v0[1] + v0[2] + v0[3] + v1[0] + v1[1] + v1[2] + v1[3];
    #pragma unroll
    for (int off = 1; off < 64; off <<= 1) s += __shfl_xor(s, off);
    const float mu = s * (1.0f / 512.0f);

    float d2 = 0.0f;
    #pragma unroll
    for (int j = 0; j < 4; ++j) {
        const float a = v0[j] - mu, bq = v1[j] - mu;
        d2 += a * a + bq * bq;
    }
    #pragma unroll
    for (int off = 1; off < 64; off <<= 1) d2 += __shfl_xor(d2, off);
    const float rstd = rsqrtf(d2 * (1.0f / 512.0f) + 1e-5f);

    f4 g0 = *(const f4*)&gamma[tid * 8];
    f4 g1 = *(const f4*)&gamma[tid * 8 + 4];
    f4 be0 = *(const f4*)&beta[tid * 8];
    f4 be1 = *(const f4*)&beta[tid * 8 + 4];
    f4 o0, o1;
    #pragma unroll
    for (int j = 0; j < 4; ++j) {
        o0[j] = (v0[j] - mu) * rstd * g0[j] + be0[j];
        o1[j] = (v1[j] - mu) * rstd * g1[j] + be1[j];
    }
    *(f4*)&out[base]     = o0;
    *(f4*)&out[base + 4] = o1;
}

// ---------------------------------------------------------------------------
extern "C" void kernel_launch(void* const* d_in, const int* in_sizes, int n_in,
                              void* d_out, int out_size, void* d_ws, size_t ws_size,
                              hipStream_t stream)
{
    const float* x     = (const float*)d_in[0];
    const int*   adj   = (const int*)  d_in[1];
    const float* Wq    = (const float*)d_in[2];
    const float* bq    = (const float*)d_in[3];
    const float* Wk    = (const float*)d_in[4];
    const float* bk    = (const float*)d_in[5];
    const float* Wv    = (const float*)d_in[6];
    const float* bv    = (const float*)d_in[7];
    const float* Wo    = (const float*)d_in[8];
    const float* bo    = (const float*)d_in[9];
    const float* gamma = (const float*)d_in[10];
    const float* beta  = (const float*)d_in[11];
    float* out = (float*)d_out;

    const size_t elems = (size_t)B_ * N_ * D_;   // 2,097,152
    float* ws = (float*)d_ws;
    float* Qb  = ws;
    float* Kb  = ws + elems;
    float* Vb  = ws + 2 * elems;
    float* ctx = ws + 3 * elems;
    float* y1  = Qb;   // Q is dead after attention; reuse for Wo output

    // Fused QKV: 4 x 32 tiles x 3 projections = 384 blocks (fills 256 CUs).
    qkv_kernel<<<dim3(4, 32, 3), 256, 0, stream>>>(
        x, Wq, bq, Wk, bk, Wv, bv, Qb, Kb, Vb);

    attn_kernel<<<dim3(N_ / 64, B_ * H_), 256, 0, stream>>>(Qb, Kb, Vb, adj, ctx);

    proj_kernel<<<dim3(4, 32), 256, 0, stream>>>(ctx, Wo, bo, y1);

    ln_kernel<<<B_ * N_, 64, 0, stream>>>(x, y1, gamma, beta, out);
}

// Round 4
// 355.278 us; speedup vs baseline: 1.7079x; 1.7079x over previous
//
#include <hip/hip_runtime.h>
#include <hip/hip_bf16.h>

// Problem constants (fixed by the reference).
#define B_  2
#define N_  2048
#define D_  512
#define H_  8
#define HD_ 64

typedef float  f4  __attribute__((ext_vector_type(4)));
typedef int    i4  __attribute__((ext_vector_type(4)));
typedef short  bf16x8 __attribute__((ext_vector_type(8)));   // 8 bf16 (4 VGPRs)
typedef float  f32x4  __attribute__((ext_vector_type(4)));   // MFMA C/D frag
typedef unsigned short u16x8 __attribute__((ext_vector_type(8)));

// float -> bf16 (round to nearest even), no header-type dependence.
static __device__ __forceinline__ unsigned short f2bf(float f) {
    union { float f; unsigned int u; } v; v.f = f;
    unsigned int r = v.u + 0x7fffu + ((v.u >> 16) & 1u);
    return (unsigned short)(r >> 16);
}

// ---------------------------------------------------------------------------
// Projection GEMM: out[r, c] = sum_k in[r, k] * W[c, k] + bias[c]
// MODE 0: fp32 out, plain [4096, 512]
// MODE 1: bf16 out in [B, H, N, HD] layout (for MFMA attention)
// Tile 128x128, BK=32, 256 threads, 8x8 micro-tile (fp32 vector math).
// ---------------------------------------------------------------------------
template <int MODE>
__device__ __forceinline__ void proj_body(
    const float* __restrict__ A, const float* __restrict__ W,
    const float* __restrict__ bias, float* __restrict__ outf,
    unsigned short* __restrict__ outh, int c0, int r0)
{
    __shared__ float As[32][132];   // [k][m]
    __shared__ float Bs[32][132];   // [k][n]

    const int tid = threadIdx.x;
    const int tx = tid & 15, ty = tid >> 4;

    float acc[8][8] = {};

    for (int kt = 0; kt < 512; kt += 32) {
        __syncthreads();
        #pragma unroll
        for (int l = 0; l < 4; ++l) {
            const int m  = (tid >> 3) + l * 32;     // 0..127
            const int k4 = (tid & 7) * 4;           // 0..28
            f4 ta = *(const f4*)&A[(size_t)(r0 + m) * 512 + kt + k4];
            As[k4 + 0][m] = ta[0]; As[k4 + 1][m] = ta[1];
            As[k4 + 2][m] = ta[2]; As[k4 + 3][m] = ta[3];
            f4 tw = *(const f4*)&W[(size_t)(c0 + m) * 512 + kt + k4];
            Bs[k4 + 0][m] = tw[0]; Bs[k4 + 1][m] = tw[1];
            Bs[k4 + 2][m] = tw[2]; Bs[k4 + 3][m] = tw[3];
        }
        __syncthreads();

        #pragma unroll 8
        for (int kk = 0; kk < 32; ++kk) {
            f4 a0 = *(const f4*)&As[kk][ty * 8];
            f4 a1 = *(const f4*)&As[kk][ty * 8 + 4];
            f4 b0 = *(const f4*)&Bs[kk][tx * 8];
            f4 b1 = *(const f4*)&Bs[kk][tx * 8 + 4];
            #pragma unroll
            for (int i = 0; i < 8; ++i) {
                const float av = (i < 4) ? a0[i] : a1[i - 4];
                #pragma unroll
                for (int j = 0; j < 8; ++j) {
                    const float bv = (j < 4) ? b0[j] : b1[j - 4];
                    acc[i][j] += av * bv;
                }
            }
        }
    }

    #pragma unroll
    for (int i = 0; i < 8; ++i) {
        const int r = r0 + ty * 8 + i;
        const int bb = r >> 11;        // / N_
        const int n  = r & (N_ - 1);
        if (MODE == 0) {
            #pragma unroll
            for (int jj = 0; jj < 8; jj += 4) {
                const int c = c0 + tx * 8 + jj;
                f4 bv = *(const f4*)&bias[c];
                f4 o;
                o[0] = acc[i][jj + 0] + bv[0];
                o[1] = acc[i][jj + 1] + bv[1];
                o[2] = acc[i][jj + 2] + bv[2];
                o[3] = acc[i][jj + 3] + bv[3];
                *(f4*)&outf[(size_t)r * 512 + c] = o;
            }
        } else {
            // bf16, [B,H,N,HD] layout; c-range of this thread stays in one head.
            const int c = c0 + tx * 8;
            const int h = c >> 6, hd = c & 63;
            f4 bv0 = *(const f4*)&bias[c];
            f4 bv1 = *(const f4*)&bias[c + 4];
            u16x8 o;
            #pragma unroll
            for (int j = 0; j < 4; ++j) {
                o[j]     = f2bf(acc[i][j]     + bv0[j]);
                o[j + 4] = f2bf(acc[i][j + 4] + bv1[j]);
            }
            *(u16x8*)&outh[(((size_t)(bb * H_ + h)) * N_ + n) * HD_ + hd] = o;
        }
    }
}

__global__ __launch_bounds__(256) void qkv_kernel(
    const float* __restrict__ x,
    const float* __restrict__ Wq, const float* __restrict__ bq,
    const float* __restrict__ Wk, const float* __restrict__ bk,
    const float* __restrict__ Wv, const float* __restrict__ bv,
    unsigned short* __restrict__ Qh, unsigned short* __restrict__ Kh,
    unsigned short* __restrict__ Vh)
{
    const int z = blockIdx.z;
    const float* W  = (z == 0) ? Wq : (z == 1) ? Wk : Wv;
    const float* bb = (z == 0) ? bq : (z == 1) ? bk : bv;
    unsigned short* dst = (z == 0) ? Qh : (z == 1) ? Kh : Vh;
    proj_body<1>(x, W, bb, nullptr, dst, blockIdx.x * 128, blockIdx.y * 128);
}

__global__ __launch_bounds__(256) void proj_kernel(
    const float* __restrict__ A, const float* __restrict__ W,
    const float* __restrict__ bias, float* __restrict__ out)
{
    proj_body<0>(A, W, bias, out, nullptr, blockIdx.x * 128, blockIdx.y * 128);
}

// ---------------------------------------------------------------------------
// MFMA masked flash attention (bf16 inputs, fp32 softmax/accum).
// Block: 256 thr = 4 waves; wave w owns q rows [q0+16w, q0+16w+16).
// K-tile = 64.  mfma_f32_16x16x32_bf16 fragments:
//   A: row = lane&15, k = (lane>>4)*8 + j   (+32 for second mfma)
//   B: col = lane&15, k = (lane>>4)*8 + j
//   C/D: col = lane&15, row = (lane>>4)*4 + reg   [verified m89/m91]
// LDS stride 72 bf16 (144 B): b128 reads land 1 lane per 4-bank group per
// phase -> conflict-free minimum throughput.
// ---------------------------------------------------------------------------
__global__ __launch_bounds__(256) void attn_kernel(
    const unsigned short* __restrict__ Q, const unsigned short* __restrict__ K,
    const unsigned short* __restrict__ V, const int* __restrict__ adj,
    float* __restrict__ ctx)
{
    __shared__ unsigned short K_lds[64][72];
    __shared__ unsigned short Vt_lds[64][72];     // transposed: [dv][k]
    __shared__ unsigned short P_lds[4][16][72];   // per-wave P tile

    const int tid  = threadIdx.x;
    const int lane = tid & 63;
    const int w    = tid >> 6;
    const int l15  = lane & 15, lhi = lane >> 4;
    const int bh = blockIdx.y;
    const int b  = bh >> 3;
    const int hh = bh & 7;
    const int q0 = blockIdx.x * 64;

    const unsigned short* Qbh = Q + (size_t)bh * N_ * HD_;
    const unsigned short* Kbh = K + (size_t)bh * N_ * HD_;
    const unsigned short* Vbh = V + (size_t)bh * N_ * HD_;
    const int* adjb = adj + (size_t)b * N_ * N_;

    // Q fragments for this wave's 16 rows, loaded once from global.
    const int qrow = q0 + w * 16 + l15;
    bf16x8 aq0 = *(const bf16x8*)&Qbh[(size_t)qrow * HD_ + lhi * 8];
    bf16x8 aq1 = *(const bf16x8*)&Qbh[(size_t)qrow * HD_ + 32 + lhi * 8];

    const int qrow_base = q0 + w * 16 + lhi * 4;   // C-tile rows of this lane

    f32x4 acc[4];      // ctx [16q x 64dv]: 4 dv-tiles
    #pragma unroll
    for (int t = 0; t < 4; ++t) acc[t] = (f32x4){0.f, 0.f, 0.f, 0.f};
    float m_r[4], l_r[4];
    const float NEG_INF = -__builtin_inff();
    #pragma unroll
    for (int r = 0; r < 4; ++r) { m_r[r] = NEG_INF; l_r[r] = 0.0f; }

    const float scale = 0.125f;

    // Adjacency prefetch registers: [r][kt]
    int adjc[4][4], adjn[4][4];
    #pragma unroll
    for (int r = 0; r < 4; ++r)
        #pragma unroll
        for (int kt = 0; kt < 4; ++kt)
            adjc[r][kt] = adjb[(size_t)(qrow_base + r) * N_ + kt * 16 + l15];

    for (int kc = 0; kc < N_; kc += 64) {
        __syncthreads();   // previous tile's LDS reads complete

        // ---- Stage K tile [64][64] bf16 -> K_lds (2x b128 per thread).
        {
            const int k  = tid & 63;
            const int c2 = tid >> 6;           // 0..3
            u16x8 k0 = *(const u16x8*)&Kbh[(size_t)(kc + k) * HD_ + c2 * 8];
            u16x8 k1 = *(const u16x8*)&Kbh[(size_t)(kc + k) * HD_ + (c2 + 4) * 8];
            *(u16x8*)&K_lds[k][c2 * 8]       = k0;
            *(u16x8*)&K_lds[k][(c2 + 4) * 8] = k1;
        }
        // ---- Stage V tile transposed -> Vt_lds (paired-k b32 writes).
        {
            const int k2  = (tid & 31) * 2;
            const int dvb = (tid >> 5) * 8;    // 0..56
            u16x8 v0 = *(const u16x8*)&Vbh[(size_t)(kc + k2) * HD_ + dvb];
            u16x8 v1 = *(const u16x8*)&Vbh[(size_t)(kc + k2 + 1) * HD_ + dvb];
            #pragma unroll
            for (int i = 0; i < 8; ++i) {
                unsigned int pair = (unsigned int)(unsigned short)v0[i] |
                                    ((unsigned int)(unsigned short)v1[i] << 16);
                *(unsigned int*)&Vt_lds[dvb + i][k2] = pair;
            }
        }

        // ---- Prefetch next tile's adjacency (wrapped; unused on last iter).
        const int kcn = (kc + 64) & (N_ - 1);
        #pragma unroll
        for (int r = 0; r < 4; ++r)
            #pragma unroll
            for (int kt = 0; kt < 4; ++kt)
                adjn[r][kt] = adjb[(size_t)(qrow_base + r) * N_ + kcn + kt * 16 + l15];

        __syncthreads();   // staging visible

        // ---- S = Q.K^T : 4 k-subtiles x (K-dim 64 = 2 mfma).
        f32x4 s[4];
        #pragma unroll
        for (int kt = 0; kt < 4; ++kt) {
            bf16x8 bk0 = *(const bf16x8*)&K_lds[kt * 16 + l15][lhi * 8];
            bf16x8 bk1 = *(const bf16x8*)&K_lds[kt * 16 + l15][32 + lhi * 8];
            f32x4 z = {0.f, 0.f, 0.f, 0.f};
            z = __builtin_amdgcn_mfma_f32_16x16x32_bf16(aq0, bk0, z, 0, 0, 0);
            s[kt] = __builtin_amdgcn_mfma_f32_16x16x32_bf16(aq1, bk1, z, 0, 0, 0);
        }

        // ---- Mask + online softmax (per lane: 4 rows x 4 k-subtiles).
        #pragma unroll
        for (int r = 0; r < 4; ++r) {
            float sm[4];
            #pragma unroll
            for (int kt = 0; kt < 4; ++kt)
                sm[kt] = adjc[r][kt] ? s[kt][r] * scale : NEG_INF;
            float mx = fmaxf(fmaxf(sm[0], sm[1]), fmaxf(sm[2], sm[3]));
            #pragma unroll
            for (int off = 1; off < 16; off <<= 1)
                mx = fmaxf(mx, __shfl_xor(mx, off));
            const float mnew = fmaxf(m_r[r], mx);
            float fac, p[4];
            if (mnew == NEG_INF) {
                fac = 1.0f;
                p[0] = p[1] = p[2] = p[3] = 0.0f;
            } else {
                fac = __expf(m_r[r] - mnew);
                #pragma unroll
                for (int kt = 0; kt < 4; ++kt)
                    p[kt] = __expf(sm[kt] - mnew);
            }
            m_r[r] = mnew;
            float rs = p[0] + p[1] + p[2] + p[3];
            #pragma unroll
            for (int off = 1; off < 16; off <<= 1)
                rs += __shfl_xor(rs, off);
            l_r[r] = l_r[r] * fac + rs;
            #pragma unroll
            for (int t = 0; t < 4; ++t) acc[t][r] *= fac;
            // P -> bf16 -> per-wave LDS (row = lhi*4+r, col = kt*16+l15).
            #pragma unroll
            for (int kt = 0; kt < 4; ++kt)
                P_lds[w][lhi * 4 + r][kt * 16 + l15] = f2bf(p[kt]);
        }

        // ---- ctx += P.V  (A-frag from P_lds, B-frag from Vt_lds).
        #pragma unroll
        for (int ks = 0; ks < 2; ++ks) {
            bf16x8 ap = *(const bf16x8*)&P_lds[w][l15][ks * 32 + lhi * 8];
            #pragma unroll
            for (int dvt = 0; dvt < 4; ++dvt) {
                bf16x8 bv = *(const bf16x8*)&Vt_lds[dvt * 16 + l15][ks * 32 + lhi * 8];
                acc[dvt] = __builtin_amdgcn_mfma_f32_16x16x32_bf16(ap, bv, acc[dvt], 0, 0, 0);
            }
        }

        // rotate adjacency prefetch
        #pragma unroll
        for (int r = 0; r < 4; ++r)
            #pragma unroll
            for (int kt = 0; kt < 4; ++kt)
                adjc[r][kt] = adjn[r][kt];
    }

    // ---- Epilogue: normalize, store ctx fp32 [B, N, D].
    #pragma unroll
    for (int r = 0; r < 4; ++r) {
        const int q = qrow_base + r;
        const float inv = (l_r[r] > 0.0f) ? 1.0f / l_r[r] : 0.0f;
        #pragma unroll
        for (int dvt = 0; dvt < 4; ++dvt)
            ctx[((size_t)(b * N_ + q)) * D_ + hh * HD_ + dvt * 16 + l15] =
                acc[dvt][r] * inv;
    }
}

// ---------------------------------------------------------------------------
// Residual + LayerNorm: out = LN(x + y1) * gamma + beta.  One wave per row.
// ---------------------------------------------------------------------------
__global__ __launch_bounds__(64) void ln_kernel(
    const float* __restrict__ x, const float* __restrict__ y1,
    const float* __restrict__ gamma, const float* __restrict__ beta,
    float* __restrict__ out)
{
    const int row = blockIdx.x;
    const int tid = threadIdx.x;
    const size_t base = (size_t)row * 512 + tid * 8;

    f4 v0 = *(const f4*)&x[base]     + *(const f4*)&y1[base];
    f4 v1 = *(const f4*)&x[base + 4] + *(const f4*)&y1[base + 4];

    float s = v0[0] + v0[1] + v0[2] + v0[3] + v1[0] + v1[1] + v1[2] + v1[3];
    #pragma unroll
    for (int off = 1; off < 64; off <<= 1) s += __shfl_xor(s, off);
    const float mu = s * (1.0f / 512.0f);

    float d2 = 0.0f;
    #pragma unroll
    for (int j = 0; j < 4; ++j) {
        const float a = v0[j] - mu, bq = v1[j] - mu;
        d2 += a * a + bq * bq;
    }
    #pragma unroll
    for (int off = 1; off < 64; off <<= 1) d2 += __shfl_xor(d2, off);
    const float rstd = rsqrtf(d2 * (1.0f / 512.0f) + 1e-5f);

    f4 g0 = *(const f4*)&gamma[tid * 8];
    f4 g1 = *(const f4*)&gamma[tid * 8 + 4];
    f4 be0 = *(const f4*)&beta[tid * 8];
    f4 be1 = *(const f4*)&beta[tid * 8 + 4];
    f4 o0, o1;
    #pragma unroll
    for (int j = 0; j < 4; ++j) {
        o0[j] = (v0[j] - mu) * rstd * g0[j] + be0[j];
        o1[j] = (v1[j] - mu) * rstd * g1[j] + be1[j];
    }
    *(f4*)&out[base]     = o0;
    *(f4*)&out[base + 4] = o1;
}

// ---------------------------------------------------------------------------
extern "C" void kernel_launch(void* const* d_in, const int* in_sizes, int n_in,
                              void* d_out, int out_size, void* d_ws, size_t ws_size,
                              hipStream_t stream)
{
    const float* x     = (const float*)d_in[0];
    const int*   adj   = (const int*)  d_in[1];
    const float* Wq    = (const float*)d_in[2];
    const float* bq    = (const float*)d_in[3];
    const float* Wk    = (const float*)d_in[4];
    const float* bk    = (const float*)d_in[5];
    const float* Wv    = (const float*)d_in[6];
    const float* bv    = (const float*)d_in[7];
    const float* Wo    = (const float*)d_in[8];
    const float* bo    = (const float*)d_in[9];
    const float* gamma = (const float*)d_in[10];
    const float* beta  = (const float*)d_in[11];
    float* out = (float*)d_out;

    const size_t elems = (size_t)B_ * N_ * D_;   // 2,097,152
    unsigned short* Qh = (unsigned short*)d_ws;
    unsigned short* Kh = Qh + elems;
    unsigned short* Vh = Kh + elems;
    float* ctx = (float*)(Vh + elems);           // 12 MB offset
    float* y1  = (float*)d_ws;                   // overlays Qh+Kh (dead post-attn)

    qkv_kernel<<<dim3(4, 32, 3), 256, 0, stream>>>(
        x, Wq, bq, Wk, bk, Wv, bv, Qh, Kh, Vh);

    attn_kernel<<<dim3(N_ / 64, B_ * H_), 256, 0, stream>>>(Qh, Kh, Vh, adj, ctx);

    proj_kernel<<<dim3(4, 32), 256, 0, stream>>>(ctx, Wo, bo, y1);

    ln_kernel<<<B_ * N_, 64, 0, stream>>>(x, y1, gamma, beta, out);
}

// Round 7
// 241.816 us; speedup vs baseline: 2.5093x; 1.4692x over previous
//
#include <hip/hip_runtime.h>
#include <hip/hip_bf16.h>

// Problem constants (fixed by the reference).
#define B_  2
#define N_  2048
#define D_  512
#define H_  8
#define HD_ 64

typedef float  f4  __attribute__((ext_vector_type(4)));
typedef int    i4  __attribute__((ext_vector_type(4)));
typedef short  bf16x8 __attribute__((ext_vector_type(8)));   // 8 bf16 (4 VGPRs)
typedef float  f32x4  __attribute__((ext_vector_type(4)));   // MFMA C/D frag
typedef unsigned short u16x8 __attribute__((ext_vector_type(8)));

// float -> bf16 (round to nearest even).
static __device__ __forceinline__ unsigned short f2bf(float f) {
    union { float f; unsigned int u; } v; v.f = f;
    unsigned int r = v.u + 0x7fffu + ((v.u >> 16) & 1u);
    return (unsigned short)(r >> 16);
}

// ---------------------------------------------------------------------------
// Prep: convert x (2M f32) and Wq/Wk/Wv/Wo (4 x 256K f32) to bf16.
// 8 elems per thread; 1536 blocks x 256 threads exactly covers 3,145,728.
// ---------------------------------------------------------------------------
__global__ __launch_bounds__(256) void prep_kernel(
    const float* __restrict__ x,
    const float* __restrict__ Wq, const float* __restrict__ Wk,
    const float* __restrict__ Wv, const float* __restrict__ Wo,
    unsigned short* __restrict__ xh, unsigned short* __restrict__ WhAll)
{
    const size_t e = ((size_t)blockIdx.x * 256 + threadIdx.x) * 8;
    const float* src;
    unsigned short* dst;
    if (e < 2097152) {            // x
        src = x + e;  dst = xh + e;
    } else {
        const size_t e2 = e - 2097152;
        const int wi = (int)(e2 >> 18);          // 262144 = 2^18 per W
        const size_t off = e2 & 262143;
        const float* Ws = (wi == 0) ? Wq : (wi == 1) ? Wk : (wi == 2) ? Wv : Wo;
        src = Ws + off;  dst = WhAll + (size_t)wi * 262144 + off;
    }
    f4 a = *(const f4*)src;
    f4 b = *(const f4*)(src + 4);
    u16x8 o;
    #pragma unroll
    for (int j = 0; j < 4; ++j) { o[j] = f2bf(a[j]); o[j + 4] = f2bf(b[j]); }
    *(u16x8*)dst = o;
}

// ---------------------------------------------------------------------------
// bf16 MFMA GEMM: C[r,c] = sum_k Ah[r,k] * Wh[c,k] + bias[c]
// Ah: [M,512] bf16 row-major; Wh: [512,512] bf16 row-major (row = out feature).
// Tile 128x128, BK=64, 256 thr = 4 waves in 2x2; wave tile 64x64 (4x4 frags
// of mfma_f32_16x16x32_bf16).  LDS pad to 72 bf16 -> <=2-way conflicts.
// OUT_MODE 0: fp32 out [M,512];  OUT_MODE 1: bf16 out [B,H,N,HD].
// C/D layout: col=lane&15, row=(lane>>4)*4+reg  [verified m89/m91].
// ---------------------------------------------------------------------------
template <int OUT_MODE>
__device__ __forceinline__ void mfma_gemm_body(
    const unsigned short* __restrict__ Ah, const unsigned short* __restrict__ Wh,
    const float* __restrict__ bias, float* __restrict__ outf,
    unsigned short* __restrict__ outh, int r0, int c0)
{
    __shared__ unsigned short Asm[128][72];
    __shared__ unsigned short Bsm[128][72];

    const int tid  = threadIdx.x;
    const int lane = tid & 63;
    const int w    = tid >> 6;
    const int wr   = w >> 1, wc = w & 1;
    const int l15  = lane & 15, lhi = lane >> 4;

    f32x4 acc[4][4];
    #pragma unroll
    for (int mi = 0; mi < 4; ++mi)
        #pragma unroll
        for (int ni = 0; ni < 4; ++ni)
            acc[mi][ni] = (f32x4){0.f, 0.f, 0.f, 0.f};

    for (int kt = 0; kt < 512; kt += 64) {
        __syncthreads();
        // Stage A rows and W rows (both k-contiguous) as bf16x8 vectors.
        #pragma unroll
        for (int i = 0; i < 4; ++i) {
            const int v   = tid + i * 256;      // 0..1023
            const int row = v >> 3;             // 0..127
            const int c8  = (v & 7) * 8;        // 0..56
            *(u16x8*)&Asm[row][c8] =
                *(const u16x8*)&Ah[(size_t)(r0 + row) * 512 + kt + c8];
            *(u16x8*)&Bsm[row][c8] =
                *(const u16x8*)&Wh[(size_t)(c0 + row) * 512 + kt + c8];
        }
        __syncthreads();

        #pragma unroll
        for (int ks = 0; ks < 2; ++ks) {
            bf16x8 a[4], bb[4];
            #pragma unroll
            for (int mi = 0; mi < 4; ++mi)
                a[mi] = *(const bf16x8*)&Asm[wr * 64 + mi * 16 + l15][ks * 32 + lhi * 8];
            #pragma unroll
            for (int ni = 0; ni < 4; ++ni)
                bb[ni] = *(const bf16x8*)&Bsm[wc * 64 + ni * 16 + l15][ks * 32 + lhi * 8];
            #pragma unroll
            for (int mi = 0; mi < 4; ++mi)
                #pragma unroll
                for (int ni = 0; ni < 4; ++ni)
                    acc[mi][ni] = __builtin_amdgcn_mfma_f32_16x16x32_bf16(
                        a[mi], bb[ni], acc[mi][ni], 0, 0, 0);
        }
    }

    // Epilogue.
    #pragma unroll
    for (int ni = 0; ni < 4; ++ni) {
        const int c = c0 + wc * 64 + ni * 16 + l15;
        const float bias_c = bias[c];
        #pragma unroll
        for (int mi = 0; mi < 4; ++mi) {
            #pragma unroll
            for (int reg = 0; reg < 4; ++reg) {
                const int r = r0 + wr * 64 + mi * 16 + lhi * 4 + reg;
                const float vv = acc[mi][ni][reg] + bias_c;
                if (OUT_MODE == 0) {
                    outf[(size_t)r * 512 + c] = vv;
                } else {
                    const int bbn = r >> 11, n = r & (N_ - 1);
                    const int h = c >> 6, hd = c & 63;
                    outh[(((size_t)(bbn * H_ + h)) * N_ + n) * HD_ + hd] = f2bf(vv);
                }
            }
        }
    }
}

// Fused QKV: blockIdx.z selects projection.
__global__ __launch_bounds__(256) void qkv_mfma_kernel(
    const unsigned short* __restrict__ xh, const unsigned short* __restrict__ WhAll,
    const float* __restrict__ bq, const float* __restrict__ bk,
    const float* __restrict__ bv,
    unsigned short* __restrict__ Qh, unsigned short* __restrict__ Kh,
    unsigned short* __restrict__ Vh)
{
    const int z = blockIdx.z;
    const unsigned short* Wh = WhAll + (size_t)z * 262144;
    const float* bias = (z == 0) ? bq : (z == 1) ? bk : bv;
    unsigned short* dst = (z == 0) ? Qh : (z == 1) ? Kh : Vh;
    mfma_gemm_body<1>(xh, Wh, bias, nullptr, dst,
                      blockIdx.y * 128, blockIdx.x * 128);
}

__global__ __launch_bounds__(256) void wo_mfma_kernel(
    const unsigned short* __restrict__ ctxh, const unsigned short* __restrict__ WhAll,
    const float* __restrict__ bo, float* __restrict__ y1)
{
    mfma_gemm_body<0>(ctxh, WhAll + 3 * 262144, bo, y1, nullptr,
                      blockIdx.y * 128, blockIdx.x * 128);
}

// ---------------------------------------------------------------------------
// MFMA masked flash attention (bf16 in, fp32 softmax/accum, bf16 ctx out).
// Core validated in round 4; only the ctx store dtype changed (fp32 -> bf16).
// ---------------------------------------------------------------------------
__global__ __launch_bounds__(256) void attn_kernel(
    const unsigned short* __restrict__ Q, const unsigned short* __restrict__ K,
    const unsigned short* __restrict__ V, const int* __restrict__ adj,
    unsigned short* __restrict__ ctxh)
{
    __shared__ unsigned short K_lds[64][72];
    __shared__ unsigned short Vt_lds[64][72];     // transposed: [dv][k]
    __shared__ unsigned short P_lds[4][16][72];   // per-wave P tile

    const int tid  = threadIdx.x;
    const int lane = tid & 63;
    const int w    = tid >> 6;
    const int l15  = lane & 15, lhi = lane >> 4;
    const int bh = blockIdx.y;
    const int b  = bh >> 3;
    const int hh = bh & 7;
    const int q0 = blockIdx.x * 64;

    const unsigned short* Qbh = Q + (size_t)bh * N_ * HD_;
    const unsigned short* Kbh = K + (size_t)bh * N_ * HD_;
    const unsigned short* Vbh = V + (size_t)bh * N_ * HD_;
    const int* adjb = adj + (size_t)b * N_ * N_;

    const int qrow = q0 + w * 16 + l15;
    bf16x8 aq0 = *(const bf16x8*)&Qbh[(size_t)qrow * HD_ + lhi * 8];
    bf16x8 aq1 = *(const bf16x8*)&Qbh[(size_t)qrow * HD_ + 32 + lhi * 8];

    const int qrow_base = q0 + w * 16 + lhi * 4;

    f32x4 acc[4];
    #pragma unroll
    for (int t = 0; t < 4; ++t) acc[t] = (f32x4){0.f, 0.f, 0.f, 0.f};
    float m_r[4], l_r[4];
    const float NEG_INF = -__builtin_inff();
    #pragma unroll
    for (int r = 0; r < 4; ++r) { m_r[r] = NEG_INF; l_r[r] = 0.0f; }

    const float scale = 0.125f;

    int adjc[4][4], adjn[4][4];
    #pragma unroll
    for (int r = 0; r < 4; ++r)
        #pragma unroll
        for (int kt = 0; kt < 4; ++kt)
            adjc[r][kt] = adjb[(size_t)(qrow_base + r) * N_ + kt * 16 + l15];

    for (int kc = 0; kc < N_; kc += 64) {
        __syncthreads();

        {   // Stage K tile [64][64] -> K_lds.
            const int k  = tid & 63;
            const int c2 = tid >> 6;
            u16x8 k0 = *(const u16x8*)&Kbh[(size_t)(kc + k) * HD_ + c2 * 8];
            u16x8 k1 = *(const u16x8*)&Kbh[(size_t)(kc + k) * HD_ + (c2 + 4) * 8];
            *(u16x8*)&K_lds[k][c2 * 8]       = k0;
            *(u16x8*)&K_lds[k][(c2 + 4) * 8] = k1;
        }
        {   // Stage V tile transposed -> Vt_lds.
            const int k2  = (tid & 31) * 2;
            const int dvb = (tid >> 5) * 8;
            u16x8 v0 = *(const u16x8*)&Vbh[(size_t)(kc + k2) * HD_ + dvb];
            u16x8 v1 = *(const u16x8*)&Vbh[(size_t)(kc + k2 + 1) * HD_ + dvb];
            #pragma unroll
            for (int i = 0; i < 8; ++i) {
                unsigned int pair = (unsigned int)(unsigned short)v0[i] |
                                    ((unsigned int)(unsigned short)v1[i] << 16);
                *(unsigned int*)&Vt_lds[dvb + i][k2] = pair;
            }
        }

        const int kcn = (kc + 64) & (N_ - 1);
        #pragma unroll
        for (int r = 0; r < 4; ++r)
            #pragma unroll
            for (int kt = 0; kt < 4; ++kt)
                adjn[r][kt] = adjb[(size_t)(qrow_base + r) * N_ + kcn + kt * 16 + l15];

        __syncthreads();

        f32x4 s[4];
        #pragma unroll
        for (int kt = 0; kt < 4; ++kt) {
            bf16x8 bk0 = *(const bf16x8*)&K_lds[kt * 16 + l15][lhi * 8];
            bf16x8 bk1 = *(const bf16x8*)&K_lds[kt * 16 + l15][32 + lhi * 8];
            f32x4 z = {0.f, 0.f, 0.f, 0.f};
            z = __builtin_amdgcn_mfma_f32_16x16x32_bf16(aq0, bk0, z, 0, 0, 0);
            s[kt] = __builtin_amdgcn_mfma_f32_16x16x32_bf16(aq1, bk1, z, 0, 0, 0);
        }

        #pragma unroll
        for (int r = 0; r < 4; ++r) {
            float sm[4];
            #pragma unroll
            for (int kt = 0; kt < 4; ++kt)
                sm[kt] = adjc[r][kt] ? s[kt][r] * scale : NEG_INF;
            float mx = fmaxf(fmaxf(sm[0], sm[1]), fmaxf(sm[2], sm[3]));
            #pragma unroll
            for (int off = 1; off < 16; off <<= 1)
                mx = fmaxf(mx, __shfl_xor(mx, off));
            const float mnew = fmaxf(m_r[r], mx);
            float fac, p[4];
            if (mnew == NEG_INF) {
                fac = 1.0f;
                p[0] = p[1] = p[2] = p[3] = 0.0f;
            } else {
                fac = __expf(m_r[r] - mnew);
                #pragma unroll
                for (int kt = 0; kt < 4; ++kt)
                    p[kt] = __expf(sm[kt] - mnew);
            }
            m_r[r] = mnew;
            float rs = p[0] + p[1] + p[2] + p[3];
            #pragma unroll
            for (int off = 1; off < 16; off <<= 1)
                rs += __shfl_xor(rs, off);
            l_r[r] = l_r[r] * fac + rs;
            #pragma unroll
            for (int t = 0; t < 4; ++t) acc[t][r] *= fac;
            #pragma unroll
            for (int kt = 0; kt < 4; ++kt)
                P_lds[w][lhi * 4 + r][kt * 16 + l15] = f2bf(p[kt]);
        }

        #pragma unroll
        for (int ks = 0; ks < 2; ++ks) {
            bf16x8 ap = *(const bf16x8*)&P_lds[w][l15][ks * 32 + lhi * 8];
            #pragma unroll
            for (int dvt = 0; dvt < 4; ++dvt) {
                bf16x8 bv = *(const bf16x8*)&Vt_lds[dvt * 16 + l15][ks * 32 + lhi * 8];
                acc[dvt] = __builtin_amdgcn_mfma_f32_16x16x32_bf16(ap, bv, acc[dvt], 0, 0, 0);
            }
        }

        #pragma unroll
        for (int r = 0; r < 4; ++r)
            #pragma unroll
            for (int kt = 0; kt < 4; ++kt)
                adjc[r][kt] = adjn[r][kt];
    }

    #pragma unroll
    for (int r = 0; r < 4; ++r) {
        const int q = qrow_base + r;
        const float inv = (l_r[r] > 0.0f) ? 1.0f / l_r[r] : 0.0f;
        #pragma unroll
        for (int dvt = 0; dvt < 4; ++dvt)
            ctxh[((size_t)(b * N_ + q)) * D_ + hh * HD_ + dvt * 16 + l15] =
                f2bf(acc[dvt][r] * inv);
    }
}

// ---------------------------------------------------------------------------
// Residual + LayerNorm: out = LN(x + y1) * gamma + beta.  One wave per row.
// ---------------------------------------------------------------------------
__global__ __launch_bounds__(64) void ln_kernel(
    const float* __restrict__ x, const float* __restrict__ y1,
    const float* __restrict__ gamma, const float* __restrict__ beta,
    float* __restrict__ out)
{
    const int row = blockIdx.x;
    const int tid = threadIdx.x;
    const size_t base = (size_t)row * 512 + tid * 8;

    f4 v0 = *(const f4*)&x[base]     + *(const f4*)&y1[base];
    f4 v1 = *(const f4*)&x[base + 4] + *(const f4*)&y1[base + 4];

    float s = v0[0] + v0[1] + v0[2] + v0[3] + v1[0] + v1[1] + v1[2] + v1[3];
    #pragma unroll
    for (int off = 1; off < 64; off <<= 1) s += __shfl_xor(s, off);
    const float mu = s * (1.0f / 512.0f);

    float d2 = 0.0f;
    #pragma unroll
    for (int j = 0; j < 4; ++j) {
        const float a = v0[j] - mu, bq = v1[j] - mu;
        d2 += a * a + bq * bq;
    }
    #pragma unroll
    for (int off = 1; off < 64; off <<= 1) d2 += __shfl_xor(d2, off);
    const float rstd = rsqrtf(d2 * (1.0f / 512.0f) + 1e-5f);

    f4 g0 = *(const f4*)&gamma[tid * 8];
    f4 g1 = *(const f4*)&gamma[tid * 8 + 4];
    f4 be0 = *(const f4*)&beta[tid * 8];
    f4 be1 = *(const f4*)&beta[tid * 8 + 4];
    f4 o0, o1;
    #pragma unroll
    for (int j = 0; j < 4; ++j) {
        o0[j] = (v0[j] - mu) * rstd * g0[j] + be0[j];
        o1[j] = (v1[j] - mu) * rstd * g1[j] + be1[j];
    }
    *(f4*)&out[base]     = o0;
    *(f4*)&out[base + 4] = o1;
}

// ---------------------------------------------------------------------------
extern "C" void kernel_launch(void* const* d_in, const int* in_sizes, int n_in,
                              void* d_out, int out_size, void* d_ws, size_t ws_size,
                              hipStream_t stream)
{
    const float* x     = (const float*)d_in[0];
    const int*   adj   = (const int*)  d_in[1];
    const float* Wq    = (const float*)d_in[2];
    const float* bq    = (const float*)d_in[3];
    const float* Wk    = (const float*)d_in[4];
    const float* bk    = (const float*)d_in[5];
    const float* Wv    = (const float*)d_in[6];
    const float* bv    = (const float*)d_in[7];
    const float* Wo    = (const float*)d_in[8];
    const float* bo    = (const float*)d_in[9];
    const float* gamma = (const float*)d_in[10];
    const float* beta  = (const float*)d_in[11];
    float* out = (float*)d_out;

    const size_t elems = (size_t)B_ * N_ * D_;   // 2,097,152
    unsigned short* Qh    = (unsigned short*)d_ws;   // bf16 segments:
    unsigned short* Kh    = Qh   + elems;
    unsigned short* Vh    = Kh   + elems;
    unsigned short* ctxh  = Vh   + elems;
    unsigned short* xh    = ctxh + elems;
    unsigned short* WhAll = xh   + elems;            // 4 x 262144
    float* y1 = (float*)Qh;    // overlay: Qh/Kh dead after attention

    // 1. Convert x + weights to bf16.
    prep_kernel<<<1536, 256, 0, stream>>>(x, Wq, Wk, Wv, Wo, xh, WhAll);

    // 2. QKV projections (bf16 MFMA).
    qkv_mfma_kernel<<<dim3(4, 32, 3), 256, 0, stream>>>(
        xh, WhAll, bq, bk, bv, Qh, Kh, Vh);

    // 3. Masked flash attention.
    attn_kernel<<<dim3(N_ / 64, B_ * H_), 256, 0, stream>>>(Qh, Kh, Vh, adj, ctxh);

    // 4. Output projection (bf16 MFMA, fp32 out).
    wo_mfma_kernel<<<dim3(4, 32), 256, 0, stream>>>(ctxh, WhAll, bo, y1);

    // 5. Residual + LayerNorm.
    ln_kernel<<<B_ * N_, 64, 0, stream>>>(x, y1, gamma, beta, out);
}